// Round 2
// baseline (167.038 us; speedup 1.0000x reference)
//
#include <hip/hip_runtime.h>
#include <hip/hip_bf16.h>

// PairDrift: B=4, N=512, D=3, H=128
// ws layout: q[4*512*128]f32 @0 (1MB) | wsBf[8192]u32 @1MB (32KB) |
//            psum1[4*512*128]f32 @1MB+32KB | psum2[...] next  (total ~3.3MB)

typedef float f32x4 __attribute__((ext_vector_type(4)));
typedef __bf16 bf16x8 __attribute__((ext_vector_type(8)));

union PKU { uint4 u; bf16x8 v; };

__device__ __forceinline__ float clamp1(float v) { return fminf(1.0f, fmaxf(-1.0f, v)); }
__device__ __forceinline__ unsigned f2bf(float f) {
    unsigned u = __float_as_uint(f);
    u += 0x7FFF + ((u >> 16) & 1);   // RNE
    return u >> 16;
}

// ---------- kernel 1: q = x @ Wp1 (no bias); and pre-swizzled bf16 Wpl frags ----------
__global__ void prep_kernel(const float* __restrict__ x, const float* __restrict__ Wp1,
                            const float* __restrict__ Wpl,
                            float* __restrict__ q, unsigned* __restrict__ wsBf) {
    int gid = blockIdx.x * 256 + threadIdx.x;
    if (blockIdx.x < 1024) {
        // q[n][h], n = b*512+j flattened (2048 rows)
        int h = gid & 127, n = gid >> 7;
        const float* xp = x + n * 3;
        q[gid] = xp[0] * Wp1[h] + xp[1] * Wp1[128 + h] + xp[2] * Wp1[256 + h];
    } else {
        int g = gid - 1024 * 256;              // 0..8191 u32 words
        int w  = g & 3;
        int l  = (g >> 2) & 63;
        int fi = g >> 8;                        // 0..31: wn*16 + nf*4 + kf
        int wn = fi >> 4, nf = (fi >> 2) & 3, kf = fi & 3;
        int n = wn * 64 + nf * 16 + (l & 15);   // output col of Wpl
        int k = kf * 32 + (l >> 4) * 8 + w * 2; // contraction index
        unsigned lo = f2bf(Wpl[k * 128 + n]);
        unsigned hi = f2bf(Wpl[(k + 1) * 128 + n]);
        wsBf[g] = lo | (hi << 16);
    }
}

// ---------- kernel 2: per (b,j): psum1 = sum_i ht(qj+bp1-qi); psum2 = sum_i ht(p1@Wpl+bpl) ----------
__global__ __launch_bounds__(256, 2) void pair_kernel(
    const float* __restrict__ q, const unsigned* __restrict__ wsBf,
    const float* __restrict__ bp1, const float* __restrict__ bpl,
    float* __restrict__ psum1, float* __restrict__ psum2)
{
    __shared__ uint4 A_lds[2048];       // 128x128 bf16, XOR-swizzled
    __shared__ float ps1[16][128];
    __shared__ float ps2[2][128];

    const int tid  = threadIdx.x;
    const int lane = tid & 63;
    const int wid  = tid >> 6;
    const int wm = wid >> 1, wn = wid & 1;
    const int bj = blockIdx.x;
    const int b  = bj >> 9;
    const float* __restrict__ qb = q + (b << 9) * 128;   // q[b, i, h]

    // persistent B fragments (Wpl), 16 frags = 64 VGPRs per wave
    bf16x8 Bf[4][4];
    #pragma unroll
    for (int nf = 0; nf < 4; ++nf)
        #pragma unroll
        for (int kf = 0; kf < 4; ++kf) {
            PKU t;
            t.u = *(const uint4*)(wsBf + ((((wn << 4) | (nf << 2) | kf) << 6) | lane) * 4);
            Bf[nf][kf] = t.v;
        }

    // A-gen mapping: thread t -> cols c*8..c*8+7, rows r = u*16 + rb
    const int c = tid & 15, rb = tid >> 4;
    float qjb[8];
    {
        const float* qj = q + bj * 128 + c * 8;
        #pragma unroll
        for (int e = 0; e < 8; ++e) qjb[e] = qj[e] + bp1[c * 8 + e];
    }
    float bplv[4];
    #pragma unroll
    for (int nf = 0; nf < 4; ++nf) bplv[nf] = bpl[wn * 64 + nf * 16 + (lane & 15)];

    float psum1r[8] = {0, 0, 0, 0, 0, 0, 0, 0};
    f32x4 acc[4][4];
    #pragma unroll
    for (int mf = 0; mf < 4; ++mf)
        #pragma unroll
        for (int nf = 0; nf < 4; ++nf) acc[mf][nf] = (f32x4){0.f, 0.f, 0.f, 0.f};
    float colsum[4] = {0, 0, 0, 0};

    for (int ch = 0; ch < 4; ++ch) {
        // ---- generate A tile: p1[i] = ht(qjb - q[i]) for 128 i's ----
        #pragma unroll
        for (int u = 0; u < 8; ++u) {
            const int r = (u << 4) | rb;
            const int i = (ch << 7) | r;
            const float4 q0 = *(const float4*)(qb + i * 128 + c * 8);
            const float4 q1 = *(const float4*)(qb + i * 128 + c * 8 + 4);
            float p[8];
            p[0] = clamp1(qjb[0] - q0.x); p[1] = clamp1(qjb[1] - q0.y);
            p[2] = clamp1(qjb[2] - q0.z); p[3] = clamp1(qjb[3] - q0.w);
            p[4] = clamp1(qjb[4] - q1.x); p[5] = clamp1(qjb[5] - q1.y);
            p[6] = clamp1(qjb[6] - q1.z); p[7] = clamp1(qjb[7] - q1.w);
            #pragma unroll
            for (int e = 0; e < 8; ++e) psum1r[e] += p[e];
            uint4 pk;
            pk.x = f2bf(p[0]) | (f2bf(p[1]) << 16);
            pk.y = f2bf(p[2]) | (f2bf(p[3]) << 16);
            pk.z = f2bf(p[4]) | (f2bf(p[5]) << 16);
            pk.w = f2bf(p[6]) | (f2bf(p[7]) << 16);
            unsigned addr = (r << 8) | (c << 4);
            addr ^= ((r & 7) << 4);          // G4 swizzle for 256B-row b128 reads
            A_lds[addr >> 4] = pk;
        }
        __syncthreads();
        // ---- MFMA: 128x128x128, wave (wm,wn) owns 64x64 ----
        #pragma unroll
        for (int kf = 0; kf < 4; ++kf) {
            bf16x8 Af[4];
            #pragma unroll
            for (int mf = 0; mf < 4; ++mf) {
                const int row = wm * 64 + mf * 16 + (lane & 15);
                unsigned addr = (row << 8) + (kf << 6) + ((lane >> 4) << 4);
                addr ^= ((row & 7) << 4);
                PKU t; t.u = A_lds[addr >> 4];
                Af[mf] = t.v;
            }
            #pragma unroll
            for (int mf = 0; mf < 4; ++mf)
                #pragma unroll
                for (int nf = 0; nf < 4; ++nf)
                    acc[mf][nf] = __builtin_amdgcn_mfma_f32_16x16x32_bf16(
                        Af[mf], Bf[nf][kf], acc[mf][nf], 0, 0, 0);
        }
        __syncthreads();
        // ---- epilogue (register-only, overlaps next A-gen): ht + row-sum ----
        #pragma unroll
        for (int mf = 0; mf < 4; ++mf)
            #pragma unroll
            for (int nf = 0; nf < 4; ++nf) {
                f32x4 a = acc[mf][nf];
                acc[mf][nf] = (f32x4){0.f, 0.f, 0.f, 0.f};
                colsum[nf] += clamp1(a.x + bplv[nf]) + clamp1(a.y + bplv[nf])
                            + clamp1(a.z + bplv[nf]) + clamp1(a.w + bplv[nf]);
            }
    }

    // ---- reductions ----
    *(float4*)(&ps1[rb][c * 8])     = make_float4(psum1r[0], psum1r[1], psum1r[2], psum1r[3]);
    *(float4*)(&ps1[rb][c * 8 + 4]) = make_float4(psum1r[4], psum1r[5], psum1r[6], psum1r[7]);
    #pragma unroll
    for (int nf = 0; nf < 4; ++nf) {
        float v = colsum[nf];
        v += __shfl_xor(v, 16);
        v += __shfl_xor(v, 32);
        if (lane < 16) ps2[wm][wn * 64 + nf * 16 + lane] = v;
    }
    __syncthreads();
    if (tid < 128) {
        float s = 0.f;
        #pragma unroll
        for (int r2 = 0; r2 < 16; ++r2) s += ps1[r2][tid];
        psum1[bj * 128 + tid] = s;
        psum2[bj * 128 + tid] = ps2[0][tid] + ps2[1][tid];
    }
}

// ---------- kernel 3: s-path + combine + skip ----------
__global__ void combine_kernel(
    const float* __restrict__ x,
    const float* __restrict__ Ws1, const float* __restrict__ bs1,
    const float* __restrict__ Wc1s, const float* __restrict__ bc1s,
    const float* __restrict__ Wc1p, const float* __restrict__ bc1p,
    const float* __restrict__ Wc2s, const float* __restrict__ bc2s,
    const float* __restrict__ Wc2p, const float* __restrict__ bc2p,
    const float* __restrict__ Wskip,
    const float* __restrict__ psum1, const float* __restrict__ psum2,
    float* __restrict__ out)
{
    __shared__ float s1[128], p1s[128], red[6];
    const int h = threadIdx.x;       // 0..127
    const int bj = blockIdx.x;
    const float* xj = x + bj * 3;

    float s1h = clamp1(xj[0] * Ws1[h] + xj[1] * Ws1[128 + h] + xj[2] * Ws1[256 + h] + bs1[h]);
    s1[h]  = s1h;
    p1s[h] = psum1[bj * 128 + h];
    __syncthreads();

    float s2 = bc1s[h] + 512.0f * bc1p[h];
    for (int k = 0; k < 128; ++k)
        s2 += s1[k] * Wc1s[k * 128 + h] + p1s[k] * Wc1p[k * 128 + h];
    float s3 = clamp1(s2);

    float ps2h = psum2[bj * 128 + h];
    float c0 = s3 * Wc2s[h * 3 + 0] + ps2h * Wc2p[h * 3 + 0];
    float c1 = s3 * Wc2s[h * 3 + 1] + ps2h * Wc2p[h * 3 + 1];
    float c2 = s3 * Wc2s[h * 3 + 2] + ps2h * Wc2p[h * 3 + 2];
    #pragma unroll
    for (int off = 32; off > 0; off >>= 1) {
        c0 += __shfl_down(c0, off);
        c1 += __shfl_down(c1, off);
        c2 += __shfl_down(c2, off);
    }
    if ((h & 63) == 0) {
        red[(h >> 6) * 3 + 0] = c0;
        red[(h >> 6) * 3 + 1] = c1;
        red[(h >> 6) * 3 + 2] = c2;
    }
    __syncthreads();
    if (h < 3) {
        float o = red[h] + red[3 + h];
        o += bc2s[h] + 512.0f * bc2p[h];
        o += xj[0] * Wskip[h * 3 + 0] + xj[1] * Wskip[h * 3 + 1] + xj[2] * Wskip[h * 3 + 2];
        out[bj * 3 + h] = o;
    }
}

extern "C" void kernel_launch(void* const* d_in, const int* in_sizes, int n_in,
                              void* d_out, int out_size, void* d_ws, size_t ws_size,
                              hipStream_t stream) {
    const float* x    = (const float*)d_in[0];
    const float* Ws1  = (const float*)d_in[1];
    const float* bs1  = (const float*)d_in[2];
    const float* Wp1  = (const float*)d_in[3];
    const float* bp1  = (const float*)d_in[4];
    const float* Wc1s = (const float*)d_in[5];
    const float* bc1s = (const float*)d_in[6];
    const float* Wc1p = (const float*)d_in[7];
    const float* bc1p = (const float*)d_in[8];
    const float* Wpl  = (const float*)d_in[9];
    const float* bpl  = (const float*)d_in[10];
    const float* Wc2s = (const float*)d_in[11];
    const float* bc2s = (const float*)d_in[12];
    const float* Wc2p = (const float*)d_in[13];
    const float* bc2p = (const float*)d_in[14];
    const float* Wskip= (const float*)d_in[15];

    float*    q    = (float*)d_ws;
    unsigned* wsBf = (unsigned*)((char*)d_ws + (1 << 20));
    float*    ps1  = (float*)((char*)d_ws + (1 << 20) + 32768);
    float*    ps2  = ps1 + 4 * 512 * 128;

    prep_kernel<<<1056, 256, 0, stream>>>(x, Wp1, Wpl, q, wsBf);
    pair_kernel<<<2048, 256, 0, stream>>>(q, wsBf, bp1, bpl, ps1, ps2);
    combine_kernel<<<2048, 128, 0, stream>>>(x, Ws1, bs1, Wc1s, bc1s, Wc1p, bc1p,
                                             Wc2s, bc2s, Wc2p, bc2p, Wskip,
                                             ps1, ps2, (float*)d_out);
}